// Round 11
// baseline (41874.698 us; speedup 1.0000x reference)
//
#include <hip/hip_runtime.h>

#define WGSZ 1024
#define NWG  256

namespace {
constexpr int kN = 2048;
// ws layout in floats (first 256 slots are u32 barrier counters)
constexpr size_t OFF_XC   = 256;               // conv out [4096][64]
constexpr size_t OFF_ELAH = OFF_XC   + 262144; // [256][64]
constexpr size_t OFF_CAT  = OFF_ELAH + 16384;  // [512][64] = elao|elmo
constexpr size_t OFF_ELMH = OFF_CAT  + 32768;
constexpr size_t OFF_EBLH = OFF_ELMH + 16384;
constexpr size_t OFF_EBLO = OFF_EBLH + 16384;
constexpr size_t OFF_H0   = OFF_EBLO + 16384;  // [2][256][64] ping-pong
constexpr size_t OFF_C0   = OFF_H0   + 32768;
constexpr size_t OFF_H1   = OFF_C0   + 32768;
constexpr size_t OFF_C1   = OFF_H1   + 32768;
constexpr size_t OFF_DMC  = OFF_C1   + 32768;  // dmh [64][256] batch-major
constexpr size_t OFF_DVC  = OFF_DMC  + 16384;
constexpr size_t WS_NEED  = OFF_DVC  + 16384;  // ~2.1 MB
}

__device__ __forceinline__ int bin_idx(float v) {
  float t = fmaf(v, 5.0f, 63.5f);
  int i0 = (int)floorf(t);
  int c0 = i0 - 1; c0 = c0 < 0 ? 0 : (c0 > 127 ? 127 : c0);
  int c1 = i0;     c1 = c1 < 0 ? 0 : (c1 > 127 ? 127 : c1);
  int c2 = i0 + 1; c2 = c2 < 0 ? 0 : (c2 > 127 ? 127 : c2);
  float d0 = fabsf(__fmul_rn(__fadd_rn((float)(c0 - 64), 0.5f), 0.2f) - v);
  float d1 = fabsf(__fmul_rn(__fadd_rn((float)(c1 - 64), 0.5f), 0.2f) - v);
  float d2 = fabsf(__fmul_rn(__fadd_rn((float)(c2 - 64), 0.5f), 0.2f) - v);
  int best = c0; float bd = d0;
  if (d1 < bd) { bd = d1; best = c1; }
  if (d2 < bd) { bd = d2; best = c2; }
  return best;
}

__device__ __forceinline__ float sig_np(float x) {
  return __fdiv_rn(1.0f, __fadd_rn(1.0f, expf(-x)));
}
__device__ __forceinline__ float sqf(float x) { return __fmul_rn(x, x); }

// numpy pairwise sum over 256 values at stride 64 (LDS column), exact order.
__device__ __forceinline__ float np_pw128_s64(const float* a) {
  float r0=a[0],r1=a[64],r2=a[128],r3=a[192],r4=a[256],r5=a[320],r6=a[384],r7=a[448];
  for (int i = 8; i < 128; i += 8) {
    r0=__fadd_rn(r0,a[(i+0)*64]); r1=__fadd_rn(r1,a[(i+1)*64]);
    r2=__fadd_rn(r2,a[(i+2)*64]); r3=__fadd_rn(r3,a[(i+3)*64]);
    r4=__fadd_rn(r4,a[(i+4)*64]); r5=__fadd_rn(r5,a[(i+5)*64]);
    r6=__fadd_rn(r6,a[(i+6)*64]); r7=__fadd_rn(r7,a[(i+7)*64]);
  }
  return __fadd_rn(__fadd_rn(__fadd_rn(r0,r1),__fadd_rn(r2,r3)),
                   __fadd_rn(__fadd_rn(r4,r5),__fadd_rn(r6,r7)));
}
__device__ __forceinline__ float np_sum256_s64(const float* a) {
  return __fadd_rn(np_pw128_s64(a), np_pw128_s64(a + 128 * 64));
}
__device__ __forceinline__ float np_pw128_sq_s64(const float* a) {
  float r0=sqf(a[0]),r1=sqf(a[64]),r2=sqf(a[128]),r3=sqf(a[192]);
  float r4=sqf(a[256]),r5=sqf(a[320]),r6=sqf(a[384]),r7=sqf(a[448]);
  for (int i = 8; i < 128; i += 8) {
    r0=__fadd_rn(r0,sqf(a[(i+0)*64])); r1=__fadd_rn(r1,sqf(a[(i+1)*64]));
    r2=__fadd_rn(r2,sqf(a[(i+2)*64])); r3=__fadd_rn(r3,sqf(a[(i+3)*64]));
    r4=__fadd_rn(r4,sqf(a[(i+4)*64])); r5=__fadd_rn(r5,sqf(a[(i+5)*64]));
    r6=__fadd_rn(r6,sqf(a[(i+6)*64])); r7=__fadd_rn(r7,sqf(a[(i+7)*64]));
  }
  return __fadd_rn(__fadd_rn(__fadd_rn(r0,r1),__fadd_rn(r2,r3)),
                   __fadd_rn(__fadd_rn(r4,r5),__fadd_rn(r6,r7)));
}
__device__ __forceinline__ float np_sum256_sq_s64(const float* a) {
  return __fadd_rn(np_pw128_sq_s64(a), np_pw128_sq_s64(a + 128 * 64));
}

// Grid barrier: fresh counter per site (zeroed by prep). Agent scope.
__device__ __forceinline__ void gbar(unsigned* cnt, int tid) {
  __syncthreads();
  if (tid == 0) {
    __threadfence();
    __hip_atomic_fetch_add(cnt, 1u, __ATOMIC_RELEASE, __HIP_MEMORY_SCOPE_AGENT);
    while (__hip_atomic_load(cnt, __ATOMIC_ACQUIRE,
                             __HIP_MEMORY_SCOPE_AGENT) < (unsigned)NWG)
      __builtin_amdgcn_s_sleep(2);
  }
  __syncthreads();
}

// Stage n4 float4s ws->LDS, coalesced.
__device__ __forceinline__ void stage(float* s, const float* g, int n4, int tid) {
  float4* s4 = (float4*)s;
  const float4* g4 = (const float4*)g;
  for (int i = tid; i < n4; i += WGSZ) s4[i] = g4[i];
}

// One wave row-chain: exact ascending-k, X[k][64] in LDS, lane=batch.
__device__ __forceinline__ float mm_row(const float* __restrict__ Wrow,
                                        const float* xs, int K4, int lane) {
  const float4* w4 = (const float4*)Wrow;
  float acc = 0.0f;
  #pragma unroll 8
  for (int i = 0; i < K4; ++i) {
    float4 v = w4[i];
    const float* xp = xs + (i << 8) + lane;
    acc = fmaf(v.x, xp[0],   acc);
    acc = fmaf(v.y, xp[64],  acc);
    acc = fmaf(v.z, xp[128], acc);
    acc = fmaf(v.w, xp[192], acc);
  }
  return acc;
}

__global__ void prep_kernel(unsigned* bar) {
  const int t = threadIdx.x;
  if (t < 256) bar[t] = 0u;
}

__global__ __launch_bounds__(WGSZ, 4) void planner_kernel(
    const float* __restrict__ inp_start, const float* __restrict__ map_pts,
    const float* __restrict__ ela_w1, const float* __restrict__ ela_w2,
    const float* __restrict__ conv_w, const float* __restrict__ elm_w1,
    const float* __restrict__ elm_w2, const float* __restrict__ ebl_w1,
    const float* __restrict__ ebl_w2, const float* __restrict__ lstm_wih,
    const float* __restrict__ lstm_whh, const float* __restrict__ dm_w1,
    const float* __restrict__ dm_w2, const float* __restrict__ dv_w1,
    const float* __restrict__ dv_w2, float* __restrict__ ws,
    float* __restrict__ g_out) {
  const int w    = blockIdx.x;
  const int tid  = threadIdx.x;
  const int wv   = tid >> 6, lane = tid & 63;
  unsigned* cnt  = (unsigned*)ws;

  __shared__ __align__(16) float s_big[32768];   // 128KB
  __shared__ unsigned s_mask[512];
  __shared__ __align__(16) float s_cw[800];
  __shared__ __align__(16) float s_col[512];
  __shared__ float s_mu64[64], s_den[64];
  __shared__ float s_anchor[3], s_cs[2], s_g6[6];

  int sidx = 0;
  for (int k = 0; k <= 28; ++k) {
    const int st  = (k < 28) ? k / 7 : 0;
    const bool a0f = ((k % 7) == 0);
    const int pp  = k & 1;

    // ================= PHASE A (all 256 WGs: 4 per batch) =================
    {
      const int b = w >> 2, g = w & 3;
      if (k < 28) {
        if (tid < 512) s_mask[tid] = 0u;
        if (tid < 800) s_cw[tid] = conv_w[st * 800 + tid];
      }
      if (k == 0) {
        if (tid == 0) {
          float a2 = inp_start[b * 3 + 2];
          s_anchor[0] = inp_start[b * 3 + 0];
          s_anchor[1] = inp_start[b * 3 + 1];
          s_anchor[2] = a2;
          s_cs[0] = (float)cos((double)a2);
          s_cs[1] = (float)sin((double)a2);
        }
        if (g == 0 && tid < 3) {
          g_out[b * 96 + tid] = inp_start[b * 3 + tid];
          g_out[6144 + b * 96 + tid] = 0.01f;
        }
      } else {
        const int p = k - 1, stp = p / 7, ap = p % 7;
        if (tid < 512)
          s_col[tid] = (tid < 256) ? ws[OFF_DMC + (size_t)b * 256 + tid]
                                   : ws[OFF_DVC + (size_t)b * 256 + (tid - 256)];
        __syncthreads();
        if (tid < 6) {
          const int d = tid % 3; const bool isv = tid >= 3;
          const float4* w4 = (const float4*)((isv ? dv_w2 : dm_w2) + (stp * 3 + d) * 256);
          const float* xx = s_col + (isv ? 256 : 0);
          float acc = 0.0f;
          for (int i = 0; i < 64; ++i) {
            float4 v = w4[i];
            acc = fmaf(v.x, xx[4*i],   acc); acc = fmaf(v.y, xx[4*i+1], acc);
            acc = fmaf(v.z, xx[4*i+2], acc); acc = fmaf(v.w, xx[4*i+3], acc);
          }
          s_g6[tid] = acc;
        }
        __syncthreads();
        if (tid == 0) {
          const float dlmf[3] = {2.0f, 2.0f, 0.5f};
          for (int d = 0; d < 3; ++d) {
            float avn = __fadd_rn(s_anchor[d], __fmul_rn(tanhf(s_g6[d]), dlmf[d]));
            float vvn = __fmul_rn(sig_np(s_g6[3 + d]), 0.1f);
            s_anchor[d] = avn;
            if (g == 0) {
              int o = ((b * 4 + stp) * 8 + (ap + 1)) * 3 + d;
              g_out[o] = avn; g_out[6144 + o] = vvn;
              if (ap == 6 && stp < 3) {
                int o2 = ((b * 4 + stp + 1) * 8 + 0) * 3 + d;
                g_out[o2] = avn; g_out[6144 + o2] = vvn;
              }
            }
          }
          s_cs[0] = (float)cos((double)s_anchor[2]);
          s_cs[1] = (float)sin((double)s_anchor[2]);
        }
      }
      if (k == 28) break;
      __syncthreads();
      // OGM scatter (replicated per WG)
      {
        float ax = s_anchor[0], ay = s_anchor[1], cc = s_cs[0], ss = s_cs[1];
        for (int n = tid; n < kN; n += WGSZ) {
          float mx = __fadd_rn(map_pts[n],      -ax);
          float my = __fadd_rn(map_pts[kN + n], -ay);
          float px = fmaf(ss, my, __fmul_rn(cc, mx));
          float py = fmaf(cc, my, -__fmul_rn(ss, mx));
          bool outb = (fabsf(px) > 12.8f) || (fabsf(py) > 12.8f);
          px = outb ? 0.0f : px;
          py = outb ? 0.0f : py;
          int xi = bin_idx(px), yi = bin_idx(py);
          atomicOr(&s_mask[xi * 4 + (yi >> 5)], 1u << (yi & 31));
        }
      }
      __syncthreads();
      // conv quarter: 1 px/thread, EXACT (o,ci,t) chain
      {
        const int p = (g << 10) + tid;
        const int oy = p >> 6, ox = p & 63;
        unsigned occ = 0u;
        for (int ky = 0; ky < 5; ++ky) {
          const int y = 2 * oy - 2 + ky;
          if ((unsigned)y >= 128u) continue;
          const unsigned* row = &s_mask[y * 4];
          for (int kx = 0; kx < 5; ++kx) {
            const int x = 2 * ox - 2 + kx;
            if ((unsigned)x >= 128u) continue;
            if ((row[x >> 5] >> (x & 31)) & 1u) occ |= 1u << (ky * 5 + kx);
          }
        }
        float csum = 0.0f;
        if (occ != 0u) {
          for (int o = 0; o < 8; ++o) {
            float acc = 0.0f;
            const float* wo = s_cw + o * 100;
            for (int ci = 0; ci < 4; ++ci) {
              const float* wc = wo + ci * 25;
              #pragma unroll
              for (int t = 0; t < 25; ++t)
                acc = __fadd_rn(acc, ((occ >> t) & 1u) ? wc[t] : 0.0f);
            }
            float th = tanhf(acc);
            csum = (o == 0) ? th : __fadd_rn(csum, th);
          }
        }
        ws[OFF_XC + (size_t)p * 64 + b] = csum;
      }
      // elah rows (K=3)
      if (tid < 64) {
        const int r = (g << 6) + tid;
        const float* w1r = ela_w1 + (st * 256 + r) * 3;
        float h = fmaf(s_anchor[2], w1r[2],
                  fmaf(s_anchor[1], w1r[1], __fmul_rn(s_anchor[0], w1r[0])));
        ws[OFF_ELAH + (size_t)r * 64 + b] = fmaxf(h, 0.0f);
      }
    }
    gbar(cnt + sidx, tid); ++sidx;

    // ============ PHASE B: elao (WG 0-15) + elmh (WG 16-31) ============
    if (w < 16) {
      stage(s_big, ws + OFF_ELAH, 4096, tid);
      __syncthreads();
      const int row = (w << 4) + wv;
      float acc = mm_row(ela_w2 + (size_t)(st * 256 + row) * 256, s_big, 64, lane);
      ws[OFF_CAT + (size_t)row * 64 + lane] = acc;
    } else if (w < 32) {
      const int row = ((w - 16) << 4) + wv;
      const float4* w4 = (const float4*)(elm_w1 + (size_t)(st * 256 + row) * 4096);
      float acc = 0.0f;
      for (int c = 0; c < 16; ++c) {
        __syncthreads();
        stage(s_big, ws + OFF_XC + (size_t)c * 16384, 4096, tid);
        __syncthreads();
        #pragma unroll 8
        for (int i = 0; i < 64; ++i) {
          float4 v = w4[c * 64 + i];
          const float* xp = s_big + (i << 8) + lane;
          acc = fmaf(v.x, xp[0],   acc); acc = fmaf(v.y, xp[64],  acc);
          acc = fmaf(v.z, xp[128], acc); acc = fmaf(v.w, xp[192], acc);
        }
      }
      ws[OFF_ELMH + (size_t)row * 64 + lane] = fmaxf(acc, 0.0f);
    }
    gbar(cnt + sidx, tid); ++sidx;

    // ============ PHASE C: elmo ============
    if (w < 16) {
      stage(s_big, ws + OFF_ELMH, 4096, tid);
      __syncthreads();
      const int row = (w << 4) + wv;
      float acc = mm_row(elm_w2 + (size_t)(st * 256 + row) * 256, s_big, 64, lane);
      ws[OFF_CAT + (size_t)(256 + row) * 64 + lane] = acc;
    }
    gbar(cnt + sidx, tid); ++sidx;

    // ============ PHASE D: eblh (K=512) ============
    if (w < 16) {
      stage(s_big, ws + OFF_CAT, 8192, tid);
      __syncthreads();
      const int row = (w << 4) + wv;
      float acc = mm_row(ebl_w1 + (size_t)(st * 256 + row) * 512, s_big, 128, lane);
      ws[OFF_EBLH + (size_t)row * 64 + lane] = fmaxf(acc, 0.0f);
    }
    gbar(cnt + sidx, tid); ++sidx;

    // ============ PHASE E: eblo ============
    if (w < 16) {
      stage(s_big, ws + OFF_EBLH, 4096, tid);
      __syncthreads();
      const int row = (w << 4) + wv;
      float acc = mm_row(ebl_w2 + (size_t)(st * 256 + row) * 256, s_big, 64, lane);
      ws[OFF_EBLO + (size_t)row * 64 + lane] = acc;
    }
    gbar(cnt + sidx, tid); ++sidx;

    // ====== PHASE F: LSTM layer 0 — 4 gate chains + pointwise fused ======
    if (w < 16) {
      stage(s_big, ws + OFF_EBLO, 4096, tid);
      if (!a0f) stage(s_big + 16384, ws + OFF_H0 + (size_t)pp * 16384, 4096, tid);
      __syncthreads();
      const int u = (w << 4) + wv;
      const float4* wi4 = (const float4*)(lstm_wih + (size_t)(st * 2 + 0) * 262144 + (size_t)u * 256);
      const float4* wh4 = (const float4*)(lstm_whh + (size_t)(st * 2 + 0) * 262144 + (size_t)u * 256);
      float Ai=0,Af=0,Ag=0,Ao=0,Bi=0,Bf=0,Bg=0,Bo=0;
      if (a0f) {
        #pragma unroll 4
        for (int i = 0; i < 64; ++i) {
          const float* xp = s_big + (i << 8) + lane;
          float x0=xp[0],x1=xp[64],x2=xp[128],x3=xp[192];
          float4 v;
          v=wi4[i];        Ai=fmaf(v.x,x0,Ai);Ai=fmaf(v.y,x1,Ai);Ai=fmaf(v.z,x2,Ai);Ai=fmaf(v.w,x3,Ai);
          v=wi4[i+16384];  Af=fmaf(v.x,x0,Af);Af=fmaf(v.y,x1,Af);Af=fmaf(v.z,x2,Af);Af=fmaf(v.w,x3,Af);
          v=wi4[i+32768];  Ag=fmaf(v.x,x0,Ag);Ag=fmaf(v.y,x1,Ag);Ag=fmaf(v.z,x2,Ag);Ag=fmaf(v.w,x3,Ag);
          v=wi4[i+49152];  Ao=fmaf(v.x,x0,Ao);Ao=fmaf(v.y,x1,Ao);Ao=fmaf(v.z,x2,Ao);Ao=fmaf(v.w,x3,Ao);
          v=wh4[i];        Bi=__fadd_rn(__fadd_rn(__fadd_rn(__fadd_rn(Bi,v.x),v.y),v.z),v.w);
          v=wh4[i+16384];  Bf=__fadd_rn(__fadd_rn(__fadd_rn(__fadd_rn(Bf,v.x),v.y),v.z),v.w);
          v=wh4[i+32768];  Bg=__fadd_rn(__fadd_rn(__fadd_rn(__fadd_rn(Bg,v.x),v.y),v.z),v.w);
          v=wh4[i+49152];  Bo=__fadd_rn(__fadd_rn(__fadd_rn(__fadd_rn(Bo,v.x),v.y),v.z),v.w);
        }
      } else {
        #pragma unroll 4
        for (int i = 0; i < 64; ++i) {
          const float* xp = s_big + (i << 8) + lane;
          const float* yp = xp + 16384;
          float x0=xp[0],x1=xp[64],x2=xp[128],x3=xp[192];
          float y0=yp[0],y1=yp[64],y2=yp[128],y3=yp[192];
          float4 v;
          v=wi4[i];        Ai=fmaf(v.x,x0,Ai);Ai=fmaf(v.y,x1,Ai);Ai=fmaf(v.z,x2,Ai);Ai=fmaf(v.w,x3,Ai);
          v=wi4[i+16384];  Af=fmaf(v.x,x0,Af);Af=fmaf(v.y,x1,Af);Af=fmaf(v.z,x2,Af);Af=fmaf(v.w,x3,Af);
          v=wi4[i+32768];  Ag=fmaf(v.x,x0,Ag);Ag=fmaf(v.y,x1,Ag);Ag=fmaf(v.z,x2,Ag);Ag=fmaf(v.w,x3,Ag);
          v=wi4[i+49152];  Ao=fmaf(v.x,x0,Ao);Ao=fmaf(v.y,x1,Ao);Ao=fmaf(v.z,x2,Ao);Ao=fmaf(v.w,x3,Ao);
          v=wh4[i];        Bi=fmaf(v.x,y0,Bi);Bi=fmaf(v.y,y1,Bi);Bi=fmaf(v.z,y2,Bi);Bi=fmaf(v.w,y3,Bi);
          v=wh4[i+16384];  Bf=fmaf(v.x,y0,Bf);Bf=fmaf(v.y,y1,Bf);Bf=fmaf(v.z,y2,Bf);Bf=fmaf(v.w,y3,Bf);
          v=wh4[i+32768];  Bg=fmaf(v.x,y0,Bg);Bg=fmaf(v.y,y1,Bg);Bg=fmaf(v.z,y2,Bg);Bg=fmaf(v.w,y3,Bg);
          v=wh4[i+49152];  Bo=fmaf(v.x,y0,Bo);Bo=fmaf(v.y,y1,Bo);Bo=fmaf(v.z,y2,Bo);Bo=fmaf(v.w,y3,Bo);
        }
      }
      float gi=__fadd_rn(Ai,Bi), gf=__fadd_rn(Af,Bf);
      float gg=__fadd_rn(Ag,Bg), go=__fadd_rn(Ao,Bo);
      float cprev = a0f ? 1.0f : ws[OFF_C0 + (size_t)pp * 16384 + (size_t)u * 64 + lane];
      float cl = __fadd_rn(__fmul_rn(sig_np(gf), cprev),
                           __fmul_rn(sig_np(gi), tanhf(gg)));
      float hl = __fmul_rn(sig_np(go), tanhf(cl));
      ws[OFF_H0 + (size_t)(pp ^ 1) * 16384 + (size_t)u * 64 + lane] = hl;
      ws[OFF_C0 + (size_t)(pp ^ 1) * 16384 + (size_t)u * 64 + lane] = cl;
    }
    gbar(cnt + sidx, tid); ++sidx;

    // ====== PHASE G: LSTM layer 1 (X = h0', h1_old) ======
    if (w < 16) {
      stage(s_big, ws + OFF_H0 + (size_t)(pp ^ 1) * 16384, 4096, tid);
      if (!a0f) stage(s_big + 16384, ws + OFF_H1 + (size_t)pp * 16384, 4096, tid);
      __syncthreads();
      const int u = (w << 4) + wv;
      const float4* wi4 = (const float4*)(lstm_wih + (size_t)(st * 2 + 1) * 262144 + (size_t)u * 256);
      const float4* wh4 = (const float4*)(lstm_whh + (size_t)(st * 2 + 1) * 262144 + (size_t)u * 256);
      float Ai=0,Af=0,Ag=0,Ao=0,Bi=0,Bf=0,Bg=0,Bo=0;
      if (a0f) {
        #pragma unroll 4
        for (int i = 0; i < 64; ++i) {
          const float* xp = s_big + (i << 8) + lane;
          float x0=xp[0],x1=xp[64],x2=xp[128],x3=xp[192];
          float4 v;
          v=wi4[i];        Ai=fmaf(v.x,x0,Ai);Ai=fmaf(v.y,x1,Ai);Ai=fmaf(v.z,x2,Ai);Ai=fmaf(v.w,x3,Ai);
          v=wi4[i+16384];  Af=fmaf(v.x,x0,Af);Af=fmaf(v.y,x1,Af);Af=fmaf(v.z,x2,Af);Af=fmaf(v.w,x3,Af);
          v=wi4[i+32768];  Ag=fmaf(v.x,x0,Ag);Ag=fmaf(v.y,x1,Ag);Ag=fmaf(v.z,x2,Ag);Ag=fmaf(v.w,x3,Ag);
          v=wi4[i+49152];  Ao=fmaf(v.x,x0,Ao);Ao=fmaf(v.y,x1,Ao);Ao=fmaf(v.z,x2,Ao);Ao=fmaf(v.w,x3,Ao);
          v=wh4[i];        Bi=__fadd_rn(__fadd_rn(__fadd_rn(__fadd_rn(Bi,v.x),v.y),v.z),v.w);
          v=wh4[i+16384];  Bf=__fadd_rn(__fadd_rn(__fadd_rn(__fadd_rn(Bf,v.x),v.y),v.z),v.w);
          v=wh4[i+32768];  Bg=__fadd_rn(__fadd_rn(__fadd_rn(__fadd_rn(Bg,v.x),v.y),v.z),v.w);
          v=wh4[i+49152];  Bo=__fadd_rn(__fadd_rn(__fadd_rn(__fadd_rn(Bo,v.x),v.y),v.z),v.w);
        }
      } else {
        #pragma unroll 4
        for (int i = 0; i < 64; ++i) {
          const float* xp = s_big + (i << 8) + lane;
          const float* yp = xp + 16384;
          float x0=xp[0],x1=xp[64],x2=xp[128],x3=xp[192];
          float y0=yp[0],y1=yp[64],y2=yp[128],y3=yp[192];
          float4 v;
          v=wi4[i];        Ai=fmaf(v.x,x0,Ai);Ai=fmaf(v.y,x1,Ai);Ai=fmaf(v.z,x2,Ai);Ai=fmaf(v.w,x3,Ai);
          v=wi4[i+16384];  Af=fmaf(v.x,x0,Af);Af=fmaf(v.y,x1,Af);Af=fmaf(v.z,x2,Af);Af=fmaf(v.w,x3,Af);
          v=wi4[i+32768];  Ag=fmaf(v.x,x0,Ag);Ag=fmaf(v.y,x1,Ag);Ag=fmaf(v.z,x2,Ag);Ag=fmaf(v.w,x3,Ag);
          v=wi4[i+49152];  Ao=fmaf(v.x,x0,Ao);Ao=fmaf(v.y,x1,Ao);Ao=fmaf(v.z,x2,Ao);Ao=fmaf(v.w,x3,Ao);
          v=wh4[i];        Bi=fmaf(v.x,y0,Bi);Bi=fmaf(v.y,y1,Bi);Bi=fmaf(v.z,y2,Bi);Bi=fmaf(v.w,y3,Bi);
          v=wh4[i+16384];  Bf=fmaf(v.x,y0,Bf);Bf=fmaf(v.y,y1,Bf);Bf=fmaf(v.z,y2,Bf);Bf=fmaf(v.w,y3,Bf);
          v=wh4[i+32768];  Bg=fmaf(v.x,y0,Bg);Bg=fmaf(v.y,y1,Bg);Bg=fmaf(v.z,y2,Bg);Bg=fmaf(v.w,y3,Bg);
          v=wh4[i+49152];  Bo=fmaf(v.x,y0,Bo);Bo=fmaf(v.y,y1,Bo);Bo=fmaf(v.z,y2,Bo);Bo=fmaf(v.w,y3,Bo);
        }
      }
      float gi=__fadd_rn(Ai,Bi), gf=__fadd_rn(Af,Bf);
      float gg=__fadd_rn(Ag,Bg), go=__fadd_rn(Ao,Bo);
      float cprev = a0f ? 1.0f : ws[OFF_C1 + (size_t)pp * 16384 + (size_t)u * 64 + lane];
      float cl = __fadd_rn(__fmul_rn(sig_np(gf), cprev),
                           __fmul_rn(sig_np(gi), tanhf(gg)));
      float hl = __fmul_rn(sig_np(go), tanhf(cl));
      ws[OFF_H1 + (size_t)(pp ^ 1) * 16384 + (size_t)u * 64 + lane] = hl;
      ws[OFF_C1 + (size_t)(pp ^ 1) * 16384 + (size_t)u * 64 + lane] = cl;
    }
    gbar(cnt + sidx, tid); ++sidx;

    // ====== PHASE H: LN + r + dm/dv hidden (WG 0-31) ======
    if (w < 32) {
      stage(s_big, ws + OFF_H1 + (size_t)(pp ^ 1) * 16384, 4096, tid);
      __syncthreads();
      if (tid < 64) s_mu64[tid] = __fdiv_rn(np_sum256_s64(s_big + tid), 256.0f);
      __syncthreads();
      for (int i = 0; i < 16; ++i) {
        const int u = ((tid >> 6) << 4) + i;
        float d = __fadd_rn(s_big[u * 64 + lane], -s_mu64[lane]);
        s_big[u * 64 + lane] = d;
      }
      __syncthreads();
      if (tid < 64)
        s_den[tid] = __fsqrt_rn(__fadd_rn(
            __fdiv_rn(np_sum256_sq_s64(s_big + tid), 256.0f), 1e-5f));
      __syncthreads();
      for (int i = 0; i < 16; ++i) {
        const int u = ((tid >> 6) << 4) + i;
        float r = __fadd_rn(__fdiv_rn(s_big[u * 64 + lane], s_den[lane]),
                            ws[OFF_EBLO + (size_t)u * 64 + lane]);
        s_big[u * 64 + lane] = fmaxf(r, 0.0f);
      }
      __syncthreads();
      const int row = ((w & 15) << 4) + wv;
      const float* W = ((w < 16) ? dm_w1 : dv_w1) + (size_t)(st * 256 + row) * 256;
      float acc = mm_row(W, s_big, 64, lane);
      ws[((w < 16) ? OFF_DMC : OFF_DVC) + (size_t)lane * 256 + row] =
          fmaxf(acc, 0.0f);
    }
    gbar(cnt + sidx, tid); ++sidx;
  }
}

extern "C" void kernel_launch(void* const* d_in, const int* in_sizes, int n_in,
                              void* d_out, int out_size, void* d_ws, size_t ws_size,
                              hipStream_t stream) {
  (void)in_sizes; (void)n_in; (void)out_size; (void)ws_size;
  float* wsf = (float*)d_ws;
  prep_kernel<<<dim3(1), dim3(256), 0, stream>>>((unsigned*)d_ws);
  planner_kernel<<<dim3(NWG), dim3(WGSZ), 0, stream>>>(
      (const float*)d_in[0],  (const float*)d_in[1],  (const float*)d_in[2],
      (const float*)d_in[3],  (const float*)d_in[4],  (const float*)d_in[5],
      (const float*)d_in[6],  (const float*)d_in[7],  (const float*)d_in[8],
      (const float*)d_in[9],  (const float*)d_in[10], (const float*)d_in[11],
      (const float*)d_in[12], (const float*)d_in[13], (const float*)d_in[14],
      wsf, (float*)d_out);
}

// Round 12
// 8362.501 us; speedup vs baseline: 5.0074x; 5.0074x over previous
//
#include <hip/hip_runtime.h>

#define WGSZ 1024
#define NWG  64

namespace {
constexpr int kN = 2048;
// ws layout (floats). First 2048 u32 = team barrier counters.
constexpr size_t OFF_CONV = 2048;      // [64][4096]
constexpr size_t OFF_ELAH = 264192;    // [64][256]
constexpr size_t OFF_CAT  = 280576;    // [64][512]
constexpr size_t OFF_ELMH = 313344;    // [64][256]
constexpr size_t OFF_EBLH = 329728;    // [64][256]
constexpr size_t OFF_EBLO = 346112;    // [64][256]
constexpr size_t OFF_H0   = 362496;    // [2][64][256] ping-pong
constexpr size_t OFF_H1   = 395264;    // [2][64][256]
constexpr size_t OFF_DMH  = 428032;    // [64][256]
constexpr size_t OFF_DVH  = 444416;    // [64][256]
constexpr size_t OFF_W0   = 460800;    // transposed weights
constexpr size_t TO_ELA2 = 0;
constexpr size_t TO_ELM1 = 262144;
constexpr size_t TO_ELM2 = 4456448;
constexpr size_t TO_EBL1 = 4718592;
constexpr size_t TO_EBL2 = 5242880;
constexpr size_t TO_DM1  = 5505024;
constexpr size_t TO_DV1  = 5767168;
constexpr size_t TO_WIH  = 6029312;
constexpr size_t TO_WHH  = 8126464;
constexpr size_t W_FLOATS = 10223616;
constexpr size_t WS_FULL  = OFF_W0 + W_FLOATS;   // ~42.7 MB
constexpr int XP = 9;   // LDS x pad stride
}

__device__ __forceinline__ int bin_idx(float v) {
  float t = fmaf(v, 5.0f, 63.5f);
  int i0 = (int)floorf(t);
  int c0 = i0 - 1; c0 = c0 < 0 ? 0 : (c0 > 127 ? 127 : c0);
  int c1 = i0;     c1 = c1 < 0 ? 0 : (c1 > 127 ? 127 : c1);
  int c2 = i0 + 1; c2 = c2 < 0 ? 0 : (c2 > 127 ? 127 : c2);
  float d0 = fabsf(__fmul_rn(__fadd_rn((float)(c0 - 64), 0.5f), 0.2f) - v);
  float d1 = fabsf(__fmul_rn(__fadd_rn((float)(c1 - 64), 0.5f), 0.2f) - v);
  float d2 = fabsf(__fmul_rn(__fadd_rn((float)(c2 - 64), 0.5f), 0.2f) - v);
  int best = c0; float bd = d0;
  if (d1 < bd) { bd = d1; best = c1; }
  if (d2 < bd) { bd = d2; best = c2; }
  return best;
}

__device__ __forceinline__ float sig_np(float x) {
  return __fdiv_rn(1.0f, __fadd_rn(1.0f, expf(-x)));
}
__device__ __forceinline__ float sqf(float x) { return __fmul_rn(x, x); }

__device__ __forceinline__ void fma4(float& aa, float4 w, float4 v) {
  aa = fmaf(w.x, v.x, aa); aa = fmaf(w.y, v.y, aa);
  aa = fmaf(w.z, v.z, aa); aa = fmaf(w.w, v.w, aa);
}

// numpy pairwise sum, 256 elems at LDS stride XP (k*XP + bat layout), exact.
__device__ __forceinline__ float np_pw128_s9(const float* a) {
  float r0=a[0*XP],r1=a[1*XP],r2=a[2*XP],r3=a[3*XP];
  float r4=a[4*XP],r5=a[5*XP],r6=a[6*XP],r7=a[7*XP];
  for (int i = 8; i < 128; i += 8) {
    r0=__fadd_rn(r0,a[(i+0)*XP]); r1=__fadd_rn(r1,a[(i+1)*XP]);
    r2=__fadd_rn(r2,a[(i+2)*XP]); r3=__fadd_rn(r3,a[(i+3)*XP]);
    r4=__fadd_rn(r4,a[(i+4)*XP]); r5=__fadd_rn(r5,a[(i+5)*XP]);
    r6=__fadd_rn(r6,a[(i+6)*XP]); r7=__fadd_rn(r7,a[(i+7)*XP]);
  }
  return __fadd_rn(__fadd_rn(__fadd_rn(r0,r1),__fadd_rn(r2,r3)),
                   __fadd_rn(__fadd_rn(r4,r5),__fadd_rn(r6,r7)));
}
__device__ __forceinline__ float np_sum256_s9(const float* a) {
  return __fadd_rn(np_pw128_s9(a), np_pw128_s9(a + 128 * XP));
}
__device__ __forceinline__ float np_pw128_sq_s9(const float* a) {
  float r0=sqf(a[0*XP]),r1=sqf(a[1*XP]),r2=sqf(a[2*XP]),r3=sqf(a[3*XP]);
  float r4=sqf(a[4*XP]),r5=sqf(a[5*XP]),r6=sqf(a[6*XP]),r7=sqf(a[7*XP]);
  for (int i = 8; i < 128; i += 8) {
    r0=__fadd_rn(r0,sqf(a[(i+0)*XP])); r1=__fadd_rn(r1,sqf(a[(i+1)*XP]));
    r2=__fadd_rn(r2,sqf(a[(i+2)*XP])); r3=__fadd_rn(r3,sqf(a[(i+3)*XP]));
    r4=__fadd_rn(r4,sqf(a[(i+4)*XP])); r5=__fadd_rn(r5,sqf(a[(i+5)*XP]));
    r6=__fadd_rn(r6,sqf(a[(i+6)*XP])); r7=__fadd_rn(r7,sqf(a[(i+7)*XP]));
  }
  return __fadd_rn(__fadd_rn(__fadd_rn(r0,r1),__fadd_rn(r2,r3)),
                   __fadd_rn(__fadd_rn(r4,r5),__fadd_rn(r6,r7)));
}
__device__ __forceinline__ float np_sum256_sq_s9(const float* a) {
  return __fadd_rn(np_pw128_sq_s9(a), np_pw128_sq_s9(a + 128 * XP));
}

__device__ __forceinline__ void gl_lds(const float4* g, float4* l) {
  __builtin_amdgcn_global_load_lds(
      (__attribute__((address_space(1))) void*)g,
      (__attribute__((address_space(3))) void*)l, 16, 0, 0);
}

// Team barrier (8 WGs). Fresh counter per site, zeroed by prep. Agent scope.
__device__ __forceinline__ void bat_bar(unsigned* cnt, int tid) {
  __syncthreads();
  if (tid == 0) {
    __threadfence();
    __hip_atomic_fetch_add(cnt, 1u, __ATOMIC_RELEASE, __HIP_MEMORY_SCOPE_AGENT);
    while (__hip_atomic_load(cnt, __ATOMIC_ACQUIRE,
                             __HIP_MEMORY_SCOPE_AGENT) < 8u)
      __builtin_amdgcn_s_sleep(1);
  }
  __syncthreads();
}

// Stage team X slice [8 bat][L] (ws, batch-major) -> LDS [k][8] pad XP.
__device__ __forceinline__ void stage_x(float* xl, const float* src0,
                                        int stride, int L, int tid) {
  const int bat = tid >> 7, i = tid & 127;
  const float* sp = src0 + (size_t)bat * stride;
  for (int k = i; k < L; k += 128) xl[k * XP + bat] = sp[k];
}

// 32-row matvec piece: W slice rows [R0g,R0g+32), chunks of 32 k4 (16KB),
// drained double-buffer (R5 protocol). Thread (r,bat) exact ascending chain.
__device__ float mv32(float4 (*wb)[1024], const float4* wT, const float4* wO,
                      int k4o, int Rg, int R0g, int k4base, int C,
                      const float* xl, int tid, float acc) {
  const int wid = tid >> 6, lane = tid & 63;
  const int kkw = (wid << 1) + (lane >> 5), rw = lane & 31;
  {
    const int k4g = k4base + kkw;
    if (wT) gl_lds(wT + (size_t)k4g * Rg + R0g + rw, wb[0] + wid * 64);
    else    gl_lds(wO + (size_t)(R0g + rw) * k4o + k4g, wb[0] + wid * 64);
  }
  __syncthreads();
  for (int c = 0; c < C; ++c) {
    if (c + 1 < C) {
      const int k4g = k4base + (c + 1) * 32 + kkw;
      if (wT) gl_lds(wT + (size_t)k4g * Rg + R0g + rw, wb[(c + 1) & 1] + wid * 64);
      else    gl_lds(wO + (size_t)(R0g + rw) * k4o + k4g, wb[(c + 1) & 1] + wid * 64);
    }
    if (tid < 256) {
      const float4* sb = wb[c & 1];
      const int r = tid >> 3, bat = tid & 7;
      for (int kk = 0; kk < 32; ++kk) {
        const float4 wv = sb[kk * 32 + r];
        const float* xp = xl + (size_t)((c * 32 + kk) * 4) * XP + bat;
        acc = fmaf(wv.x, xp[0], acc);
        acc = fmaf(wv.y, xp[XP], acc);
        acc = fmaf(wv.z, xp[2 * XP], acc);
        acc = fmaf(wv.w, xp[3 * XP], acc);
      }
    }
    __syncthreads();
  }
  return acc;
}

// LSTM pass: 32 units x 4 gates (rows gate*256+u), K=256. Returns 4 gate accs
// (x=i, y=f, z=g, w=o). ones=1 -> exact add-chain (h = ones).
__device__ float4 lstm_pass(float4 (*wb)[1024], const float4* wT,
                            const float4* wO, int RB, const float* xl,
                            int ones, int tid) {
  const int wid = tid >> 6, lane = tid & 63;
  const int kkw = wid >> 1, gw = ((wid & 1) << 1) + (lane >> 5), rw = lane & 31;
  float4 A; A.x = 0.0f; A.y = 0.0f; A.z = 0.0f; A.w = 0.0f;
  {
    const int k4g = kkw;
    if (wT) gl_lds(wT + ((size_t)k4g << 13) + RB + (gw << 8) + rw, wb[0] + wid * 64);
    else    gl_lds(wO + ((size_t)(RB + (gw << 8) + rw) << 6) + k4g, wb[0] + wid * 64);
  }
  __syncthreads();
  for (int c = 0; c < 8; ++c) {
    if (c + 1 < 8) {
      const int k4g = (c + 1) * 8 + kkw;
      if (wT) gl_lds(wT + ((size_t)k4g << 13) + RB + (gw << 8) + rw,
                     wb[(c + 1) & 1] + wid * 64);
      else    gl_lds(wO + ((size_t)(RB + (gw << 8) + rw) << 6) + k4g,
                     wb[(c + 1) & 1] + wid * 64);
    }
    if (tid < 256) {
      const float4* sb = wb[c & 1];
      const int u = tid >> 3, bat = tid & 7;
      for (int kk = 0; kk < 8; ++kk) {
        const float4 wi = sb[kk * 128 + u];
        const float4 wf = sb[kk * 128 + 32 + u];
        const float4 wg = sb[kk * 128 + 64 + u];
        const float4 wo = sb[kk * 128 + 96 + u];
        if (ones) {
          A.x = __fadd_rn(__fadd_rn(__fadd_rn(__fadd_rn(A.x, wi.x), wi.y), wi.z), wi.w);
          A.y = __fadd_rn(__fadd_rn(__fadd_rn(__fadd_rn(A.y, wf.x), wf.y), wf.z), wf.w);
          A.z = __fadd_rn(__fadd_rn(__fadd_rn(__fadd_rn(A.z, wg.x), wg.y), wg.z), wg.w);
          A.w = __fadd_rn(__fadd_rn(__fadd_rn(__fadd_rn(A.w, wo.x), wo.y), wo.z), wo.w);
        } else {
          const float* xp = xl + (size_t)((c * 8 + kk) * 4) * XP + bat;
          const float x0 = xp[0], x1 = xp[XP], x2 = xp[2 * XP], x3 = xp[3 * XP];
          A.x = fmaf(wi.x, x0, A.x); A.x = fmaf(wi.y, x1, A.x);
          A.x = fmaf(wi.z, x2, A.x); A.x = fmaf(wi.w, x3, A.x);
          A.y = fmaf(wf.x, x0, A.y); A.y = fmaf(wf.y, x1, A.y);
          A.y = fmaf(wf.z, x2, A.y); A.y = fmaf(wf.w, x3, A.y);
          A.z = fmaf(wg.x, x0, A.z); A.z = fmaf(wg.y, x1, A.z);
          A.z = fmaf(wg.z, x2, A.z); A.z = fmaf(wg.w, x3, A.z);
          A.w = fmaf(wo.x, x0, A.w); A.w = fmaf(wo.y, x1, A.w);
          A.w = fmaf(wo.z, x2, A.w); A.w = fmaf(wo.w, x3, A.w);
        }
      }
    }
    __syncthreads();
  }
  return A;
}

// ---------------- prep: zero counters + transpose weights ----------------
struct TransArgs {
  const float* src[9];
  float*       dst[9];
  int          n4[9];
  int          rmask[9];
  int          rshift[9];
  int          K[9];
};

__global__ void prep_kernel(TransArgs a, unsigned* bar, int nmat) {
  const int gtid = blockIdx.x * blockDim.x + threadIdx.x;
  const int gsz  = gridDim.x * blockDim.x;
  for (int i = gtid; i < 2048; i += gsz) bar[i] = 0u;
  for (int m = 0; m < nmat; ++m) {
    const float* __restrict__ src = a.src[m];
    float4* __restrict__ dst = (float4*)a.dst[m];
    const int n = a.n4[m], rm = a.rmask[m], rs = a.rshift[m], K = a.K[m];
    for (int i = gtid; i < n; i += gsz) {
      const int r = i & rm, k4 = i >> rs;
      const float* s = src + (size_t)r * K + (size_t)k4 * 4;
      float4 v; v.x = s[0]; v.y = s[1]; v.z = s[2]; v.w = s[3];
      dst[i] = v;
    }
  }
}

// 64 WGs: team t = wg&7 (8 WGs j = wg>>3, batches 8t..8t+7; WG j owns batch
// 8t+j's OGM/conv/heads/anchor, and row-slice 32j of every matvec).
__global__ __launch_bounds__(WGSZ, 4) void planner_kernel(
    const float* __restrict__ inp_start, const float* __restrict__ map_pts,
    const float* __restrict__ ela_w1, const float* __restrict__ ela_w2,
    const float* __restrict__ conv_w, const float* __restrict__ elm_w1,
    const float* __restrict__ elm_w2, const float* __restrict__ ebl_w1,
    const float* __restrict__ ebl_w2, const float* __restrict__ lstm_wih,
    const float* __restrict__ lstm_whh, const float* __restrict__ dm_w1,
    const float* __restrict__ dm_w2, const float* __restrict__ dv_w1,
    const float* __restrict__ dv_w2, float* __restrict__ ws,
    int useT, float* __restrict__ g_out) {
  const int wg  = blockIdx.x;
  const int t   = wg & 7, j = wg >> 3;
  const int b0  = t * 8, b_own = b0 + j;
  const int R0  = j * 32;           // row slice within 256
  const int tid = threadIdx.x;
  unsigned* cnt = (unsigned*)ws + t * 256;
  const float* w0 = ws + OFF_W0;

  __shared__ __align__(16) float4 s_wbuf[2][1024];  // 32 KB
  __shared__ __align__(16) float s_x[1024 * XP];    // 36 KB
  __shared__ __align__(16) float s_xh[256 * XP];    // 9 KB
  __shared__ unsigned s_mask[512];
  __shared__ __align__(16) float s_cw[800];
  __shared__ __align__(16) float s_state[2][32][8]; // c-state, WG-local units
  __shared__ __align__(16) float s_col[512];
  __shared__ float s_mu8[8], s_den8[8];
  __shared__ float s_anchor[3], s_cs[2], s_g6[6];

  if (tid == 0) {
    float a2 = inp_start[b_own * 3 + 2];
    s_anchor[0] = inp_start[b_own * 3 + 0];
    s_anchor[1] = inp_start[b_own * 3 + 1];
    s_anchor[2] = a2;
    s_cs[0] = (float)cos((double)a2);
    s_cs[1] = (float)sin((double)a2);
  }
  if (tid < 3) {
    g_out[b_own * 96 + tid] = inp_start[b_own * 3 + tid];
    g_out[6144 + b_own * 96 + tid] = 0.01f;
  }
  __syncthreads();

  int sidx = 0;
  for (int k = 0; k < 28; ++k) {
    const int st = k / 7, a = k % 7;
    const bool a0f = (a == 0);
    const int pp = k & 1;

    // ---- phase A (WG-local): OGM + conv + elah for b_own ----
    if (tid < 512) s_mask[tid] = 0u;
    if (tid < 800) s_cw[tid] = conv_w[st * 800 + tid];
    __syncthreads();
    {
      float ax = s_anchor[0], ay = s_anchor[1], cc = s_cs[0], ss = s_cs[1];
      for (int n = tid; n < kN; n += WGSZ) {
        float mx = __fadd_rn(map_pts[n],      -ax);
        float my = __fadd_rn(map_pts[kN + n], -ay);
        float px = fmaf(ss, my, __fmul_rn(cc, mx));
        float py = fmaf(cc, my, -__fmul_rn(ss, mx));
        bool outb = (fabsf(px) > 12.8f) || (fabsf(py) > 12.8f);
        px = outb ? 0.0f : px;
        py = outb ? 0.0f : py;
        int xi = bin_idx(px), yi = bin_idx(py);
        atomicOr(&s_mask[xi * 4 + (yi >> 5)], 1u << (yi & 31));
      }
    }
    __syncthreads();
    for (int q = 0; q < 4; ++q) {
      const int p = tid + (q << 10);
      const int oy = p >> 6, ox = p & 63;
      unsigned occ = 0u;
      for (int ky = 0; ky < 5; ++ky) {
        const int y = 2 * oy - 2 + ky;
        if ((unsigned)y >= 128u) continue;
        const unsigned* row = &s_mask[y * 4];
        for (int kx = 0; kx < 5; ++kx) {
          const int x = 2 * ox - 2 + kx;
          if ((unsigned)x >= 128u) continue;
          if ((row[x >> 5] >> (x & 31)) & 1u) occ |= 1u << (ky * 5 + kx);
        }
      }
      float csum = 0.0f;
      if (occ != 0u) {
        for (int o = 0; o < 8; ++o) {
          float acc = 0.0f;
          const float* wo = s_cw + o * 100;
          for (int ci = 0; ci < 4; ++ci) {
            const float* wc = wo + ci * 25;
            #pragma unroll
            for (int tt = 0; tt < 25; ++tt)
              acc = __fadd_rn(acc, ((occ >> tt) & 1u) ? wc[tt] : 0.0f);
          }
          float th = tanhf(acc);
          csum = (o == 0) ? th : __fadd_rn(csum, th);
        }
      }
      ws[OFF_CONV + (size_t)b_own * 4096 + p] = csum;
    }
    if (tid < 256) {
      const float* w1r = ela_w1 + (st * 256 + tid) * 3;
      float h = fmaf(s_anchor[2], w1r[2],
                fmaf(s_anchor[1], w1r[1], __fmul_rn(s_anchor[0], w1r[0])));
      ws[OFF_ELAH + (size_t)b_own * 256 + tid] = fmaxf(h, 0.0f);
    }
    bat_bar(cnt + sidx, tid); ++sidx;   // S1

    // ---- phase B: ela2 -> cat[0:256]; elm1 -> elmh ----
    {
      const int R0g = st * 256 + R0;
      stage_x(s_x, ws + OFF_ELAH + (size_t)b0 * 256, 256, 256, tid);
      float acc = mv32(s_wbuf, useT ? (const float4*)(w0 + TO_ELA2) : nullptr,
                       (const float4*)ela_w2, 64, 1024, R0g, 0, 2, s_x, tid, 0.0f);
      if (tid < 256) {
        const int r = tid >> 3, bat = tid & 7;
        ws[OFF_CAT + (size_t)(b0 + bat) * 512 + R0 + r] = acc;
      }
      float ae = 0.0f;
      for (int s = 0; s < 4; ++s) {
        stage_x(s_x, ws + OFF_CONV + (size_t)b0 * 4096 + s * 1024, 4096, 1024, tid);
        ae = mv32(s_wbuf, useT ? (const float4*)(w0 + TO_ELM1) : nullptr,
                  (const float4*)elm_w1, 1024, 1024, R0g, s * 256, 8, s_x, tid, ae);
      }
      if (tid < 256) {
        const int r = tid >> 3, bat = tid & 7;
        ws[OFF_ELMH + (size_t)(b0 + bat) * 256 + R0 + r] = fmaxf(ae, 0.0f);
      }
    }
    bat_bar(cnt + sidx, tid); ++sidx;   // S2

    // ---- phase C: elm2 -> cat[256:512] ----
    {
      stage_x(s_x, ws + OFF_ELMH + (size_t)b0 * 256, 256, 256, tid);
      float acc = mv32(s_wbuf, useT ? (const float4*)(w0 + TO_ELM2) : nullptr,
                       (const float4*)elm_w2, 64, 1024, st * 256 + R0, 0, 2, s_x, tid, 0.0f);
      if (tid < 256) {
        const int r = tid >> 3, bat = tid & 7;
        ws[OFF_CAT + (size_t)(b0 + bat) * 512 + 256 + R0 + r] = acc;
      }
    }
    bat_bar(cnt + sidx, tid); ++sidx;   // S3

    // ---- phase D: ebl1 (K=512) -> eblh ----
    {
      stage_x(s_x, ws + OFF_CAT + (size_t)b0 * 512, 512, 512, tid);
      float acc = mv32(s_wbuf, useT ? (const float4*)(w0 + TO_EBL1) : nullptr,
                       (const float4*)ebl_w1, 128, 1024, st * 256 + R0, 0, 4, s_x, tid, 0.0f);
      if (tid < 256) {
        const int r = tid >> 3, bat = tid & 7;
        ws[OFF_EBLH + (size_t)(b0 + bat) * 256 + R0 + r] = fmaxf(acc, 0.0f);
      }
    }
    bat_bar(cnt + sidx, tid); ++sidx;   // S4

    // ---- phase E: ebl2 -> eblo ----
    {
      stage_x(s_x, ws + OFF_EBLH + (size_t)b0 * 256, 256, 256, tid);
      float acc = mv32(s_wbuf, useT ? (const float4*)(w0 + TO_EBL2) : nullptr,
                       (const float4*)ebl_w2, 64, 1024, st * 256 + R0, 0, 2, s_x, tid, 0.0f);
      if (tid < 256) {
        const int r = tid >> 3, bat = tid & 7;
        ws[OFF_EBLO + (size_t)(b0 + bat) * 256 + R0 + r] = acc;
      }
    }
    bat_bar(cnt + sidx, tid); ++sidx;   // S5

    // ---- phase F/G: LSTM layers, units [32j,32j+32) ----
    for (int l = 0; l < 2; ++l) {
      const int RB = (st * 2 + l) * 1024 + R0;
      if (l == 0) stage_x(s_x, ws + OFF_EBLO + (size_t)b0 * 256, 256, 256, tid);
      else        stage_x(s_x, ws + OFF_H0 + (size_t)(pp ^ 1) * 16384 + (size_t)b0 * 256,
                          256, 256, tid);
      if (!a0f) {
        const size_t hsrc = (l == 0 ? OFF_H0 : OFF_H1) + (size_t)pp * 16384;
        stage_x(s_xh, ws + hsrc + (size_t)b0 * 256, 256, 256, tid);
      }
      float4 A = lstm_pass(s_wbuf, useT ? (const float4*)(w0 + TO_WIH) : nullptr,
                           (const float4*)lstm_wih, RB, s_x, 0, tid);
      float4 B = lstm_pass(s_wbuf, useT ? (const float4*)(w0 + TO_WHH) : nullptr,
                           (const float4*)lstm_whh, RB, s_xh, a0f ? 1 : 0, tid);
      if (tid < 256) {
        const int u = tid >> 3, bat = tid & 7;
        float gi = __fadd_rn(A.x, B.x), gf = __fadd_rn(A.y, B.y);
        float gg = __fadd_rn(A.z, B.z), go = __fadd_rn(A.w, B.w);
        float cprev = a0f ? 1.0f : s_state[l][u][bat];
        float cl = __fadd_rn(__fmul_rn(sig_np(gf), cprev),
                             __fmul_rn(sig_np(gi), tanhf(gg)));
        float hl = __fmul_rn(sig_np(go), tanhf(cl));
        s_state[l][u][bat] = cl;
        const size_t hdst = (l == 0 ? OFF_H0 : OFF_H1) + (size_t)(pp ^ 1) * 16384;
        ws[hdst + (size_t)(b0 + bat) * 256 + R0 + u] = hl;
      }
      bat_bar(cnt + sidx, tid); ++sidx;   // S6 (l=0), S7 (l=1)
    }

    // ---- phase H: LN + r (replicated) + dm/dv row slices ----
    {
      stage_x(s_x, ws + OFF_H1 + (size_t)(pp ^ 1) * 16384 + (size_t)b0 * 256,
              256, 256, tid);
      stage_x(s_xh, ws + OFF_EBLO + (size_t)b0 * 256, 256, 256, tid);
      __syncthreads();
      if (tid < 8) s_mu8[tid] = __fdiv_rn(np_sum256_s9(s_x + tid), 256.0f);
      __syncthreads();
      {
        const int kk = tid >> 3, bat = tid & 7;
        float d0 = __fadd_rn(s_x[kk * XP + bat], -s_mu8[bat]);
        float d1 = __fadd_rn(s_x[(kk + 128) * XP + bat], -s_mu8[bat]);
        s_x[kk * XP + bat] = d0;
        s_x[(kk + 128) * XP + bat] = d1;
      }
      __syncthreads();
      if (tid < 8) {
        float v = __fdiv_rn(np_sum256_sq_s9(s_x + tid), 256.0f);
        s_den8[tid] = __fsqrt_rn(__fadd_rn(v, 1e-5f));
      }
      __syncthreads();
      {
        const int kk = tid >> 3, bat = tid & 7;
        float r0 = __fadd_rn(__fdiv_rn(s_x[kk * XP + bat], s_den8[bat]),
                             s_xh[kk * XP + bat]);
        float r1 = __fadd_rn(__fdiv_rn(s_x[(kk + 128) * XP + bat], s_den8[bat]),
                             s_xh[(kk + 128) * XP + bat]);
        s_x[kk * XP + bat] = fmaxf(r0, 0.0f);
        s_x[(kk + 128) * XP + bat] = fmaxf(r1, 0.0f);
      }
      const int R0g = st * 256 + R0;
      float am = mv32(s_wbuf, useT ? (const float4*)(w0 + TO_DM1) : nullptr,
                      (const float4*)dm_w1, 64, 1024, R0g, 0, 2, s_x, tid, 0.0f);
      if (tid < 256) {
        const int r = tid >> 3, bat = tid & 7;
        ws[OFF_DMH + (size_t)(b0 + bat) * 256 + R0 + r] = fmaxf(am, 0.0f);
      }
      float av = mv32(s_wbuf, useT ? (const float4*)(w0 + TO_DV1) : nullptr,
                      (const float4*)dv_w1, 64, 1024, R0g, 0, 2, s_x, tid, 0.0f);
      if (tid < 256) {
        const int r = tid >> 3, bat = tid & 7;
        ws[OFF_DVH + (size_t)(b0 + bat) * 256 + R0 + r] = fmaxf(av, 0.0f);
      }
    }
    bat_bar(cnt + sidx, tid); ++sidx;   // S8

    // ---- phase I (WG-local): heads + anchor update for b_own ----
    if (tid < 512)
      s_col[tid] = ws[(tid < 256 ? OFF_DMH : OFF_DVH) +
                      (size_t)b_own * 256 + (tid & 255)];
    __syncthreads();
    if (tid < 6) {
      const int d = tid % 3; const bool isv = tid >= 3;
      const float4* w4 = (const float4*)((isv ? dv_w2 : dm_w2) + (st * 3 + d) * 256);
      const float4* xx = (const float4*)(s_col + (isv ? 256 : 0));
      float acc = 0.0f;
      for (int i = 0; i < 64; ++i) fma4(acc, w4[i], xx[i]);
      s_g6[tid] = acc;
    }
    __syncthreads();
    if (tid == 0) {
      const float dlmf[3] = {2.0f, 2.0f, 0.5f};
      for (int d = 0; d < 3; ++d) {
        float avn = __fadd_rn(s_anchor[d], __fmul_rn(tanhf(s_g6[d]), dlmf[d]));
        float vvn = __fmul_rn(sig_np(s_g6[3 + d]), 0.1f);
        s_anchor[d] = avn;
        int o = ((b_own * 4 + st) * 8 + (a + 1)) * 3 + d;
        g_out[o] = avn;
        g_out[6144 + o] = vvn;
        if (a == 6 && st < 3) {
          int o2 = ((b_own * 4 + st + 1) * 8 + 0) * 3 + d;
          g_out[o2] = avn;
          g_out[6144 + o2] = vvn;
        }
      }
      s_cs[0] = (float)cos((double)s_anchor[2]);
      s_cs[1] = (float)sin((double)s_anchor[2]);
    }
    __syncthreads();
  }
}

extern "C" void kernel_launch(void* const* d_in, const int* in_sizes, int n_in,
                              void* d_out, int out_size, void* d_ws, size_t ws_size,
                              hipStream_t stream) {
  (void)in_sizes; (void)n_in; (void)out_size;
  float* wsf = (float*)d_ws;
  const int useT = (ws_size >= WS_FULL * sizeof(float)) ? 1 : 0;

  TransArgs ta;
  const float* srcs[9] = {
      (const float*)d_in[3],  (const float*)d_in[5],  (const float*)d_in[6],
      (const float*)d_in[7],  (const float*)d_in[8],  (const float*)d_in[11],
      (const float*)d_in[13], (const float*)d_in[9],  (const float*)d_in[10]};
  float* w0 = wsf + OFF_W0;
  float* dsts[9] = {w0 + TO_ELA2, w0 + TO_ELM1, w0 + TO_ELM2, w0 + TO_EBL1,
                    w0 + TO_EBL2, w0 + TO_DM1,  w0 + TO_DV1,  w0 + TO_WIH,
                    w0 + TO_WHH};
  const int n4s[9] = {65536, 1048576, 65536, 131072, 65536, 65536, 65536,
                      524288, 524288};
  const int rms[9] = {1023, 1023, 1023, 1023, 1023, 1023, 1023, 8191, 8191};
  const int rss[9] = {10, 10, 10, 10, 10, 10, 10, 13, 13};
  const int Ks[9]  = {256, 4096, 256, 512, 256, 256, 256, 256, 256};
  for (int m = 0; m < 9; ++m) {
    ta.src[m] = srcs[m]; ta.dst[m] = dsts[m]; ta.n4[m] = n4s[m];
    ta.rmask[m] = rms[m]; ta.rshift[m] = rss[m]; ta.K[m] = Ks[m];
  }
  prep_kernel<<<dim3(1024), dim3(256), 0, stream>>>(
      ta, (unsigned*)d_ws, useT ? 9 : 0);

  planner_kernel<<<dim3(NWG), dim3(WGSZ), 0, stream>>>(
      (const float*)d_in[0],  (const float*)d_in[1],  (const float*)d_in[2],
      (const float*)d_in[3],  (const float*)d_in[4],  (const float*)d_in[5],
      (const float*)d_in[6],  (const float*)d_in[7],  (const float*)d_in[8],
      (const float*)d_in[9],  (const float*)d_in[10], (const float*)d_in[11],
      (const float*)d_in[12], (const float*)d_in[13], (const float*)d_in[14],
      wsf, useT, (float*)d_out);
}